// Round 11
// baseline (194.798 us; speedup 1.0000x reference)
//
#include <hip/hip_runtime.h>

#define L_DIM 1024
#define B_DIM 256
#define D_DIM 768
#define K_DIM 768
#define NTILES (K_DIM / 32)
#define WN    (768 * 768)

typedef _Float16 half8 __attribute__((ext_vector_type(8)));
typedef float    floatx4 __attribute__((ext_vector_type(4)));

__device__ __forceinline__ ushort f2h(float f) {
    _Float16 h = (_Float16)f;
    return __builtin_bit_cast(ushort, h);
}

__device__ __forceinline__ void gl16(const ushort* g, ushort* l) {
    __builtin_amdgcn_global_load_lds(
        (const __attribute__((address_space(1))) unsigned int*)g,
        (__attribute__((address_space(3))) unsigned int*)l, 16, 0, 0);
}

// ---------------------------------------------------------------------------
// K1: blocks 0..511 = reduce over B (2 l-rows/block, lockstep NT sweep,
// single coherent front); blocks 512..1279 = cast W to f16.
// Block 0 resets the cross-kernel flags.
// ---------------------------------------------------------------------------
__global__ __launch_bounds__(384)
void reduce_and_cast(const float* __restrict__ x,
                     const int* __restrict__ mask,
                     const float* __restrict__ gpt,
                     const float* __restrict__ Wh, const float* __restrict__ Wp,
                     ushort* __restrict__ Vh,
                     ushort* __restrict__ WhH, ushort* __restrict__ WpH,
                     float* __restrict__ pos_cnt,
                     unsigned* __restrict__ counter, unsigned* __restrict__ rowcnt)
{
    const int tid = threadIdx.x;

    if (blockIdx.x >= 512) {
        const int idx = ((blockIdx.x - 512) * 384 + tid) * 4;
        const float4 v = (idx < WN) ? *(const float4*)(Wh + idx)
                                    : *(const float4*)(Wp + (idx - WN));
        ushort4 o;
        o.x = f2h(v.x); o.y = f2h(v.y); o.z = f2h(v.z); o.w = f2h(v.w);
        if (idx < WN) *(ushort4*)(WhH + idx) = o;
        else          *(ushort4*)(WpH + (idx - WN)) = o;
        return;
    }

    if (blockIdx.x == 0) {
        if (tid == 0) *counter = 0u;
        if (tid < 16) rowcnt[tid] = 0u;
    }

    __shared__ int mS[256][2];
    const int l0 = blockIdx.x * 2;
    if (tid < 256)
        *(int2*)&mS[tid][0] = *(const int2*)(mask + (size_t)tid * L_DIM + l0);
    __syncthreads();

    const int row = tid / 192;       // 0..1
    const int t   = tid % 192;
    const int d0  = t * 4;
    const int l   = l0 + row;

    const size_t bstride = (size_t)L_DIM * D_DIM;
    const float* xp = x + (size_t)l * D_DIM + d0;

    floatx4 pos = {0.f, 0.f, 0.f, 0.f};
    floatx4 tot = {0.f, 0.f, 0.f, 0.f};
    float cnt = 0.f;

    #pragma unroll 16
    for (int b = 0; b < B_DIM; ++b) {
        const floatx4 v = __builtin_nontemporal_load((const floatx4*)(xp + (size_t)b * bstride));
        const float fm = (float)mS[b][row];
        tot += v;
        pos[0] = fmaf(fm, v[0], pos[0]);
        pos[1] = fmaf(fm, v[1], pos[1]);
        pos[2] = fmaf(fm, v[2], pos[2]);
        pos[3] = fmaf(fm, v[3], pos[3]);
        cnt += fm;
    }

    const float inv_p = 0.5f / fmaxf(cnt, 1.0f);
    const float inv_a = 0.5f / fmaxf((float)B_DIM - cnt, 1.0f);

    const float4 g4  = *(const float4*)(gpt + (size_t)l * D_DIM + d0);
    const float4 gl4 = *(const float4*)(gpt + (size_t)L_DIM * D_DIM + d0);

    ushort4 ph, ah;
    ph.x = f2h(pos[0] * inv_p + 0.5f * g4.x);
    ph.y = f2h(pos[1] * inv_p + 0.5f * g4.y);
    ph.z = f2h(pos[2] * inv_p + 0.5f * g4.z);
    ph.w = f2h(pos[3] * inv_p + 0.5f * g4.w);
    ah.x = f2h((tot[0] - pos[0]) * inv_a + 0.5f * gl4.x);
    ah.y = f2h((tot[1] - pos[1]) * inv_a + 0.5f * gl4.y);
    ah.z = f2h((tot[2] - pos[2]) * inv_a + 0.5f * gl4.z);
    ah.w = f2h((tot[3] - pos[3]) * inv_a + 0.5f * gl4.w);

    *(ushort4*)(Vh + (size_t)l * D_DIM + d0) = ph;
    *(ushort4*)(Vh + (size_t)(L_DIM + l) * D_DIM + d0) = ah;

    if (t == 0) pos_cnt[l] = cnt;
}

// ---------------------------------------------------------------------------
// Merged 2-layer f16 MFMA GEMM, 192 blocks x 256 threads.
// Blocks 0..95  (layer 1): H = relu(V @ Wh^T + b_h), f16; signal rowcnt[ry].
// Blocks 96..191(layer 2): wait rowcnt[ry]==6; OUT = H @ Wp^T + b_p;
//   proto rows -> masked d_out; anti rows -> colsum Partial; last anti
//   block (counter) finalizes the anti output row.
// 128x128 tile, 4 waves of 64x64 (4x4 frags 16x16x32 f16), BK=32, gl_lds
// staging with XOR-swizzled global k-chunk source, LDS double buffer.
// ---------------------------------------------------------------------------
__global__ __launch_bounds__(256)
void gemm_fused(const ushort* __restrict__ Vh, const ushort* __restrict__ WhH,
                const float* __restrict__ b_h,
                ushort* __restrict__ Hh, const ushort* __restrict__ WpH,
                const float* __restrict__ b_p,
                float* __restrict__ OutF, float* __restrict__ Partial,
                const float* __restrict__ cnt,
                unsigned* __restrict__ counter, unsigned* __restrict__ rowcnt)
{
    __shared__ ushort lds[2][8192];   // [buf][ A:128x32 | B:128x32 ]
    __shared__ float  colsum[4][64];
    __shared__ float  red[256];
    __shared__ unsigned lastflag;

    const int tid   = threadIdx.x;
    const int lane  = tid & 63;
    const int wid   = tid >> 6;
    const bool first = blockIdx.x < 96;
    const int bid   = first ? blockIdx.x : blockIdx.x - 96;
    const int cx    = bid % 6;
    const int ry    = bid / 6;
    const int brow  = ry * 128;
    const int bcol  = cx * 128;
    const int wr    = (wid >> 1) * 64;
    const int wc    = (wid & 1) * 64;

    const ushort* Amat = first ? Vh  : Hh;
    const ushort* Bmat = first ? WhH : WpH;
    const float*  bias = first ? b_h : b_p;

    if (!first) {
        if (tid == 0) {
            while (atomicAdd(&rowcnt[ry], 0u) < 6u) { __builtin_amdgcn_s_sleep(8); }
        }
        __syncthreads();
        __threadfence();   // acquire H writes
    }

    const int srow = tid >> 2;
    const int slot = tid & 3;
    const int sk   = (slot ^ ((srow >> 1) & 3)) * 8;   // swizzled k-chunk

    const ushort* pA0 = Amat + (size_t)(brow + srow) * K_DIM + sk;
    const ushort* pA1 = Amat + (size_t)(brow + 64 + srow) * K_DIM + sk;
    const ushort* pB0 = Bmat + (size_t)(bcol + srow) * K_DIM + sk;
    const ushort* pB1 = Bmat + (size_t)(bcol + 64 + srow) * K_DIM + sk;

    const int ldst = tid * 8;

    const int q   = lane >> 4;
    const int r15 = lane & 15;
    const int swz = ((q ^ ((r15 >> 1) & 3)) << 3);
    const int fA  = (wr + r15) * 32 + swz;            // + mi*512
    const int fB  = 4096 + (wc + r15) * 32 + swz;     // + ni*512

    floatx4 acc[4][4] = {};

    gl16(pA0, &lds[0][ldst]);
    gl16(pA1, &lds[0][2048 + ldst]);
    gl16(pB0, &lds[0][4096 + ldst]);
    gl16(pB1, &lds[0][6144 + ldst]);
    __syncthreads();

    for (int t = 0; t < NTILES; ++t) {
        const int cur = t & 1;
        if (t + 1 < NTILES) {
            const int ko = (t + 1) * 32;
            const int nxt = cur ^ 1;
            gl16(pA0 + ko, &lds[nxt][ldst]);
            gl16(pA1 + ko, &lds[nxt][2048 + ldst]);
            gl16(pB0 + ko, &lds[nxt][4096 + ldst]);
            gl16(pB1 + ko, &lds[nxt][6144 + ldst]);
        }
        half8 a[4], b[4];
        #pragma unroll
        for (int i = 0; i < 4; ++i) {
            a[i] = *(half8*)&lds[cur][fA + i * 512];
            b[i] = *(half8*)&lds[cur][fB + i * 512];
        }
        #pragma unroll
        for (int mi = 0; mi < 4; ++mi)
            #pragma unroll
            for (int ni = 0; ni < 4; ++ni)
                acc[mi][ni] = __builtin_amdgcn_mfma_f32_16x16x32_f16(a[mi], b[ni], acc[mi][ni], 0, 0, 0);
        __syncthreads();
    }

    if (first) {
        #pragma unroll
        for (int mi = 0; mi < 4; ++mi) {
            #pragma unroll
            for (int ni = 0; ni < 4; ++ni) {
                const int col   = bcol + wc + ni * 16 + r15;
                const int rbase = brow + wr + mi * 16 + (q << 2);
                const float bv = bias[col];
                #pragma unroll
                for (int r = 0; r < 4; ++r)
                    Hh[(size_t)(rbase + r) * D_DIM + col] = f2h(fmaxf(acc[mi][ni][r] + bv, 0.f));
            }
        }
        __syncthreads();                 // drain all H stores (vmcnt 0)
        if (tid == 0) {
            __threadfence();             // release H
            atomicAdd(&rowcnt[ry], 1u);
        }
    } else if (brow < L_DIM) {
        #pragma unroll
        for (int mi = 0; mi < 4; ++mi) {
            #pragma unroll
            for (int ni = 0; ni < 4; ++ni) {
                const int col   = bcol + wc + ni * 16 + r15;
                const int rbase = brow + wr + mi * 16 + (q << 2);
                const float bv = bias[col];
                #pragma unroll
                for (int r = 0; r < 4; ++r) {
                    const int row = rbase + r;
                    OutF[(size_t)row * D_DIM + col] =
                        (cnt[row] > 0.f) ? (acc[mi][ni][r] + bv) : 0.f;
                }
            }
        }
    } else {
        // anti half: weighted column sums over this block's 128 rows
        float s[4] = {0.f, 0.f, 0.f, 0.f};
        #pragma unroll
        for (int mi = 0; mi < 4; ++mi) {
            const int rbase = brow + wr + mi * 16 + (q << 2);
            #pragma unroll
            for (int r = 0; r < 4; ++r) {
                const float w = (cnt[rbase + r - L_DIM] < 255.5f) ? 1.0f : 0.0f;
                #pragma unroll
                for (int ni = 0; ni < 4; ++ni) {
                    const int col = bcol + wc + ni * 16 + r15;
                    s[ni] = fmaf(w, acc[mi][ni][r] + bias[col], s[ni]);
                }
            }
        }
        #pragma unroll
        for (int ni = 0; ni < 4; ++ni) {
            s[ni] += __shfl_down(s[ni], 32);
            s[ni] += __shfl_down(s[ni], 16);
            if (lane < 16) colsum[wid][ni * 16 + lane] = s[ni];
        }
        __syncthreads();
        if (tid < 128) {
            const float v = (tid < 64)
                ? colsum[0][tid] + colsum[2][tid]
                : colsum[1][tid - 64] + colsum[3][tid - 64];
            Partial[(size_t)(ry - 8) * D_DIM + bcol + tid] = v;
        }
        __threadfence();
        __syncthreads();
        if (tid == 0) lastflag = (atomicAdd(counter, 1u) == 47u) ? 1u : 0u;
        __syncthreads();
        if (lastflag) {
            __threadfence();
            float w = 0.f;
            for (int i = tid; i < L_DIM; i += 256)
                w += (cnt[i] < 255.5f) ? 1.0f : 0.0f;
            red[tid] = w;
            __syncthreads();
            for (int st = 128; st > 0; st >>= 1) {
                if (tid < st) red[tid] += red[tid + st];
                __syncthreads();
            }
            const float wsum = fmaxf(red[0], 1.0f);
            #pragma unroll
            for (int j = 0; j < 3; ++j) {
                const int d = tid + j * 256;
                float sm = 0.f;
                #pragma unroll
                for (int pp = 0; pp < 8; ++pp)
                    sm += Partial[(size_t)pp * D_DIM + d];
                OutF[(size_t)L_DIM * D_DIM + d] = sm / wsum;
            }
        }
    }
}

// ---------------------------------------------------------------------------
extern "C" void kernel_launch(void* const* d_in, const int* in_sizes, int n_in,
                              void* d_out, int out_size, void* d_ws, size_t ws_size,
                              hipStream_t stream) {
    const float* x    = (const float*)d_in[0];
    const int*   mask = (const int*)d_in[1];
    const float* gpt  = (const float*)d_in[2];
    const float* W_h  = (const float*)d_in[3];
    const float* b_h  = (const float*)d_in[4];
    const float* W_p  = (const float*)d_in[5];
    const float* b_p  = (const float*)d_in[6];
    float* out = (float*)d_out;

    char* p = (char*)d_ws;
    ushort* Vh   = (ushort*)p; p += (size_t)2 * L_DIM * D_DIM * 2;
    ushort* Hh   = (ushort*)p; p += (size_t)2 * L_DIM * D_DIM * 2;
    ushort* WhH  = (ushort*)p; p += (size_t)WN * 2;
    ushort* WpH  = (ushort*)p; p += (size_t)WN * 2;
    float*  Part = (float*)p;  p += (size_t)8 * D_DIM * 4;
    float*  cnt  = (float*)p;  p += (size_t)L_DIM * 4;
    unsigned* counter = (unsigned*)p; p += 64;
    unsigned* rowcnt  = (unsigned*)p;

    reduce_and_cast<<<1280, 384, 0, stream>>>(x, mask, gpt, W_h, W_p,
                                              Vh, WhH, WpH, cnt, counter, rowcnt);

    gemm_fused<<<192, 256, 0, stream>>>(Vh, WhH, b_h, Hh, WpH, b_p,
                                        out, Part, cnt, counter, rowcnt);
}

// Round 12
// 192.206 us; speedup vs baseline: 1.0135x; 1.0135x over previous
//
#include <hip/hip_runtime.h>

#define L_DIM 1024
#define B_DIM 256
#define D_DIM 768
#define K_DIM 768
#define NTILES (K_DIM / 32)
#define WN    (768 * 768)

typedef _Float16 half8 __attribute__((ext_vector_type(8)));
typedef float    floatx4 __attribute__((ext_vector_type(4)));

__device__ __forceinline__ ushort f2h(float f) {
    _Float16 h = (_Float16)f;
    return __builtin_bit_cast(ushort, h);
}

__device__ __forceinline__ void gl16(const ushort* g, ushort* l) {
    __builtin_amdgcn_global_load_lds(
        (const __attribute__((address_space(1))) unsigned int*)g,
        (__attribute__((address_space(3))) unsigned int*)l, 16, 0, 0);
}

// ---------------------------------------------------------------------------
// K1 (exact R10 shape): blocks 0..255 = reduce over B (4 l-rows/block,
// lockstep NT sweep, single coherent front, 12KB contiguous per block/step);
// blocks 256..639 = cast W to f16. Block 0 resets cross-kernel flags.
// ---------------------------------------------------------------------------
__global__ __launch_bounds__(768)
void reduce_and_cast(const float* __restrict__ x,
                     const int* __restrict__ mask,
                     const float* __restrict__ gpt,
                     const float* __restrict__ Wh, const float* __restrict__ Wp,
                     ushort* __restrict__ Vh,
                     ushort* __restrict__ WhH, ushort* __restrict__ WpH,
                     float* __restrict__ pos_cnt,
                     unsigned* __restrict__ counter, unsigned* __restrict__ rowcnt)
{
    const int tid = threadIdx.x;

    if (blockIdx.x >= 256) {
        const int idx = ((blockIdx.x - 256) * 768 + tid) * 4;
        const float4 v = (idx < WN) ? *(const float4*)(Wh + idx)
                                    : *(const float4*)(Wp + (idx - WN));
        ushort4 o;
        o.x = f2h(v.x); o.y = f2h(v.y); o.z = f2h(v.z); o.w = f2h(v.w);
        if (idx < WN) *(ushort4*)(WhH + idx) = o;
        else          *(ushort4*)(WpH + (idx - WN)) = o;
        return;
    }

    if (blockIdx.x == 0) {
        if (tid == 0) *counter = 0u;
        if (tid < 16) rowcnt[tid] = 0u;
    }

    __shared__ int mS[256][4];
    const int l0 = blockIdx.x * 4;
    if (tid < 256)
        *(int4*)&mS[tid][0] = *(const int4*)(mask + (size_t)tid * L_DIM + l0);
    __syncthreads();

    const int row = tid / 192;       // 0..3
    const int t   = tid % 192;
    const int d0  = t * 4;
    const int l   = l0 + row;

    const size_t bstride = (size_t)L_DIM * D_DIM;
    const float* xp = x + (size_t)l * D_DIM + d0;

    floatx4 pos = {0.f, 0.f, 0.f, 0.f};
    floatx4 tot = {0.f, 0.f, 0.f, 0.f};
    float cnt = 0.f;

    #pragma unroll 16
    for (int b = 0; b < B_DIM; ++b) {
        const floatx4 v = __builtin_nontemporal_load((const floatx4*)(xp + (size_t)b * bstride));
        const float fm = (float)mS[b][row];
        tot += v;
        pos[0] = fmaf(fm, v[0], pos[0]);
        pos[1] = fmaf(fm, v[1], pos[1]);
        pos[2] = fmaf(fm, v[2], pos[2]);
        pos[3] = fmaf(fm, v[3], pos[3]);
        cnt += fm;
    }

    const float inv_p = 0.5f / fmaxf(cnt, 1.0f);
    const float inv_a = 0.5f / fmaxf((float)B_DIM - cnt, 1.0f);

    const float4 g4  = *(const float4*)(gpt + (size_t)l * D_DIM + d0);
    const float4 gl4 = *(const float4*)(gpt + (size_t)L_DIM * D_DIM + d0);

    ushort4 ph, ah;
    ph.x = f2h(pos[0] * inv_p + 0.5f * g4.x);
    ph.y = f2h(pos[1] * inv_p + 0.5f * g4.y);
    ph.z = f2h(pos[2] * inv_p + 0.5f * g4.z);
    ph.w = f2h(pos[3] * inv_p + 0.5f * g4.w);
    ah.x = f2h((tot[0] - pos[0]) * inv_a + 0.5f * gl4.x);
    ah.y = f2h((tot[1] - pos[1]) * inv_a + 0.5f * gl4.y);
    ah.z = f2h((tot[2] - pos[2]) * inv_a + 0.5f * gl4.z);
    ah.w = f2h((tot[3] - pos[3]) * inv_a + 0.5f * gl4.w);

    *(ushort4*)(Vh + (size_t)l * D_DIM + d0) = ph;
    *(ushort4*)(Vh + (size_t)(L_DIM + l) * D_DIM + d0) = ah;

    if (t == 0) pos_cnt[l] = cnt;
}

// ---------------------------------------------------------------------------
// Merged 2-layer f16 MFMA GEMM, 192 blocks x 256 threads (all co-resident).
// Blocks 0..95  (layer 1): H = relu(V @ Wh^T + b_h), f16; signal rowcnt[ry].
// Blocks 96..191(layer 2): wait rowcnt[ry]==6; OUT = H @ Wp^T + b_p;
//   proto rows -> masked d_out; anti rows -> colsum Partial; last anti
//   block (counter) finalizes the anti output row.
// 128x128 tile, 4 waves of 64x64 (4x4 frags 16x16x32 f16), BK=32, gl_lds
// staging with XOR-swizzled global k-chunk source, LDS double buffer.
// ---------------------------------------------------------------------------
__global__ __launch_bounds__(256)
void gemm_fused(const ushort* __restrict__ Vh, const ushort* __restrict__ WhH,
                const float* __restrict__ b_h,
                ushort* __restrict__ Hh, const ushort* __restrict__ WpH,
                const float* __restrict__ b_p,
                float* __restrict__ OutF, float* __restrict__ Partial,
                const float* __restrict__ cnt,
                unsigned* __restrict__ counter, unsigned* __restrict__ rowcnt)
{
    __shared__ ushort lds[2][8192];   // [buf][ A:128x32 | B:128x32 ]
    __shared__ float  colsum[4][64];
    __shared__ float  red[256];
    __shared__ unsigned lastflag;

    const int tid   = threadIdx.x;
    const int lane  = tid & 63;
    const int wid   = tid >> 6;
    const bool first = blockIdx.x < 96;
    const int bid   = first ? blockIdx.x : blockIdx.x - 96;
    const int cx    = bid % 6;
    const int ry    = bid / 6;
    const int brow  = ry * 128;
    const int bcol  = cx * 128;
    const int wr    = (wid >> 1) * 64;
    const int wc    = (wid & 1) * 64;

    const ushort* Amat = first ? Vh  : Hh;
    const ushort* Bmat = first ? WhH : WpH;
    const float*  bias = first ? b_h : b_p;

    if (!first) {
        if (tid == 0) {
            while (atomicAdd(&rowcnt[ry], 0u) < 6u) { __builtin_amdgcn_s_sleep(8); }
        }
        __syncthreads();
        __threadfence();   // acquire H writes
    }

    const int srow = tid >> 2;
    const int slot = tid & 3;
    const int sk   = (slot ^ ((srow >> 1) & 3)) * 8;   // swizzled k-chunk

    const ushort* pA0 = Amat + (size_t)(brow + srow) * K_DIM + sk;
    const ushort* pA1 = Amat + (size_t)(brow + 64 + srow) * K_DIM + sk;
    const ushort* pB0 = Bmat + (size_t)(bcol + srow) * K_DIM + sk;
    const ushort* pB1 = Bmat + (size_t)(bcol + 64 + srow) * K_DIM + sk;

    const int ldst = tid * 8;

    const int q   = lane >> 4;
    const int r15 = lane & 15;
    const int swz = ((q ^ ((r15 >> 1) & 3)) << 3);
    const int fA  = (wr + r15) * 32 + swz;            // + mi*512
    const int fB  = 4096 + (wc + r15) * 32 + swz;     // + ni*512

    floatx4 acc[4][4] = {};

    gl16(pA0, &lds[0][ldst]);
    gl16(pA1, &lds[0][2048 + ldst]);
    gl16(pB0, &lds[0][4096 + ldst]);
    gl16(pB1, &lds[0][6144 + ldst]);
    __syncthreads();

    for (int t = 0; t < NTILES; ++t) {
        const int cur = t & 1;
        if (t + 1 < NTILES) {
            const int ko = (t + 1) * 32;
            const int nxt = cur ^ 1;
            gl16(pA0 + ko, &lds[nxt][ldst]);
            gl16(pA1 + ko, &lds[nxt][2048 + ldst]);
            gl16(pB0 + ko, &lds[nxt][4096 + ldst]);
            gl16(pB1 + ko, &lds[nxt][6144 + ldst]);
        }
        half8 a[4], b[4];
        #pragma unroll
        for (int i = 0; i < 4; ++i) {
            a[i] = *(half8*)&lds[cur][fA + i * 512];
            b[i] = *(half8*)&lds[cur][fB + i * 512];
        }
        #pragma unroll
        for (int mi = 0; mi < 4; ++mi)
            #pragma unroll
            for (int ni = 0; ni < 4; ++ni)
                acc[mi][ni] = __builtin_amdgcn_mfma_f32_16x16x32_f16(a[mi], b[ni], acc[mi][ni], 0, 0, 0);
        __syncthreads();
    }

    if (first) {
        #pragma unroll
        for (int mi = 0; mi < 4; ++mi) {
            #pragma unroll
            for (int ni = 0; ni < 4; ++ni) {
                const int col   = bcol + wc + ni * 16 + r15;
                const int rbase = brow + wr + mi * 16 + (q << 2);
                const float bv = bias[col];
                #pragma unroll
                for (int r = 0; r < 4; ++r)
                    Hh[(size_t)(rbase + r) * D_DIM + col] = f2h(fmaxf(acc[mi][ni][r] + bv, 0.f));
            }
        }
        __syncthreads();                 // all threads' H stores issued
        if (tid == 0) {
            __threadfence();             // release H
            atomicAdd(&rowcnt[ry], 1u);
        }
    } else if (brow < L_DIM) {
        #pragma unroll
        for (int mi = 0; mi < 4; ++mi) {
            #pragma unroll
            for (int ni = 0; ni < 4; ++ni) {
                const int col   = bcol + wc + ni * 16 + r15;
                const int rbase = brow + wr + mi * 16 + (q << 2);
                const float bv = bias[col];
                #pragma unroll
                for (int r = 0; r < 4; ++r) {
                    const int row = rbase + r;
                    OutF[(size_t)row * D_DIM + col] =
                        (cnt[row] > 0.f) ? (acc[mi][ni][r] + bv) : 0.f;
                }
            }
        }
    } else {
        // anti half: weighted column sums over this block's 128 rows
        float s[4] = {0.f, 0.f, 0.f, 0.f};
        #pragma unroll
        for (int mi = 0; mi < 4; ++mi) {
            const int rbase = brow + wr + mi * 16 + (q << 2);
            #pragma unroll
            for (int r = 0; r < 4; ++r) {
                const float w = (cnt[rbase + r - L_DIM] < 255.5f) ? 1.0f : 0.0f;
                #pragma unroll
                for (int ni = 0; ni < 4; ++ni) {
                    const int col = bcol + wc + ni * 16 + r15;
                    s[ni] = fmaf(w, acc[mi][ni][r] + bias[col], s[ni]);
                }
            }
        }
        #pragma unroll
        for (int ni = 0; ni < 4; ++ni) {
            s[ni] += __shfl_down(s[ni], 32);
            s[ni] += __shfl_down(s[ni], 16);
            if (lane < 16) colsum[wid][ni * 16 + lane] = s[ni];
        }
        __syncthreads();
        if (tid < 128) {
            const float v = (tid < 64)
                ? colsum[0][tid] + colsum[2][tid]
                : colsum[1][tid - 64] + colsum[3][tid - 64];
            Partial[(size_t)(ry - 8) * D_DIM + bcol + tid] = v;
        }
        __threadfence();
        __syncthreads();
        if (tid == 0) lastflag = (atomicAdd(counter, 1u) == 47u) ? 1u : 0u;
        __syncthreads();
        if (lastflag) {
            __threadfence();
            float w = 0.f;
            for (int i = tid; i < L_DIM; i += 256)
                w += (cnt[i] < 255.5f) ? 1.0f : 0.0f;
            red[tid] = w;
            __syncthreads();
            for (int st = 128; st > 0; st >>= 1) {
                if (tid < st) red[tid] += red[tid + st];
                __syncthreads();
            }
            const float wsum = fmaxf(red[0], 1.0f);
            #pragma unroll
            for (int j = 0; j < 3; ++j) {
                const int d = tid + j * 256;
                float sm = 0.f;
                #pragma unroll
                for (int pp = 0; pp < 8; ++pp)
                    sm += Partial[(size_t)pp * D_DIM + d];
                OutF[(size_t)L_DIM * D_DIM + d] = sm / wsum;
            }
        }
    }
}

// ---------------------------------------------------------------------------
extern "C" void kernel_launch(void* const* d_in, const int* in_sizes, int n_in,
                              void* d_out, int out_size, void* d_ws, size_t ws_size,
                              hipStream_t stream) {
    const float* x    = (const float*)d_in[0];
    const int*   mask = (const int*)d_in[1];
    const float* gpt  = (const float*)d_in[2];
    const float* W_h  = (const float*)d_in[3];
    const float* b_h  = (const float*)d_in[4];
    const float* W_p  = (const float*)d_in[5];
    const float* b_p  = (const float*)d_in[6];
    float* out = (float*)d_out;

    char* p = (char*)d_ws;
    ushort* Vh   = (ushort*)p; p += (size_t)2 * L_DIM * D_DIM * 2;
    ushort* Hh   = (ushort*)p; p += (size_t)2 * L_DIM * D_DIM * 2;
    ushort* WhH  = (ushort*)p; p += (size_t)WN * 2;
    ushort* WpH  = (ushort*)p; p += (size_t)WN * 2;
    float*  Part = (float*)p;  p += (size_t)8 * D_DIM * 4;
    float*  cnt  = (float*)p;  p += (size_t)L_DIM * 4;
    unsigned* counter = (unsigned*)p; p += 64;
    unsigned* rowcnt  = (unsigned*)p;

    reduce_and_cast<<<640, 768, 0, stream>>>(x, mask, gpt, W_h, W_p,
                                             Vh, WhH, WpH, cnt, counter, rowcnt);

    gemm_fused<<<192, 256, 0, stream>>>(Vh, WhH, b_h, Hh, WpH, b_p,
                                        out, Part, cnt, counter, rowcnt);
}

// Round 13
// 176.713 us; speedup vs baseline: 1.1023x; 1.0877x over previous
//
#include <hip/hip_runtime.h>

#define L_DIM 1024
#define B_DIM 256
#define D_DIM 768
#define K_DIM 768
#define NTILES (K_DIM / 32)
#define WN    (768 * 768)

typedef _Float16 half8 __attribute__((ext_vector_type(8)));
typedef float    floatx4 __attribute__((ext_vector_type(4)));

__device__ __forceinline__ ushort f2h(float f) {
    _Float16 h = (_Float16)f;
    return __builtin_bit_cast(ushort, h);
}

__device__ __forceinline__ void gl16(const ushort* g, ushort* l) {
    __builtin_amdgcn_global_load_lds(
        (const __attribute__((address_space(1))) unsigned int*)g,
        (__attribute__((address_space(3))) unsigned int*)l, 16, 0, 0);
}

// ---------------------------------------------------------------------------
// K1 fused (champion R10 config): blocks 0..255 = reduce over B
// (4 l-rows/block, lockstep NT sweep, single coherent front); blocks
// 256..639 = cast W to f16. Emits V as single f16. Resets the counter.
// ---------------------------------------------------------------------------
__global__ __launch_bounds__(768)
void reduce_and_cast(const float* __restrict__ x,
                     const int* __restrict__ mask,
                     const float* __restrict__ gpt,
                     const float* __restrict__ Wh, const float* __restrict__ Wp,
                     ushort* __restrict__ Vh,
                     ushort* __restrict__ WhH, ushort* __restrict__ WpH,
                     float* __restrict__ pos_cnt, unsigned* __restrict__ counter)
{
    const int tid = threadIdx.x;

    if (blockIdx.x >= 256) {
        const int idx = ((blockIdx.x - 256) * 768 + tid) * 4;
        const float4 v = (idx < WN) ? *(const float4*)(Wh + idx)
                                    : *(const float4*)(Wp + (idx - WN));
        ushort4 o;
        o.x = f2h(v.x); o.y = f2h(v.y); o.z = f2h(v.z); o.w = f2h(v.w);
        if (idx < WN) *(ushort4*)(WhH + idx) = o;
        else          *(ushort4*)(WpH + (idx - WN)) = o;
        return;
    }

    if (blockIdx.x == 0 && tid == 0) *counter = 0u;

    __shared__ int mS[256][4];
    const int l0 = blockIdx.x * 4;
    if (tid < 256)
        *(int4*)&mS[tid][0] = *(const int4*)(mask + (size_t)tid * L_DIM + l0);
    __syncthreads();

    const int row = tid / 192;       // 0..3
    const int t   = tid % 192;
    const int d0  = t * 4;
    const int l   = l0 + row;

    const size_t bstride = (size_t)L_DIM * D_DIM;
    const float* xp = x + (size_t)l * D_DIM + d0;

    floatx4 pos = {0.f, 0.f, 0.f, 0.f};
    floatx4 tot = {0.f, 0.f, 0.f, 0.f};
    float cnt = 0.f;

    #pragma unroll 16
    for (int b = 0; b < B_DIM; ++b) {
        const floatx4 v = __builtin_nontemporal_load((const floatx4*)(xp + (size_t)b * bstride));
        const float fm = (float)mS[b][row];
        tot += v;
        pos[0] = fmaf(fm, v[0], pos[0]);
        pos[1] = fmaf(fm, v[1], pos[1]);
        pos[2] = fmaf(fm, v[2], pos[2]);
        pos[3] = fmaf(fm, v[3], pos[3]);
        cnt += fm;
    }

    const float inv_p = 0.5f / fmaxf(cnt, 1.0f);
    const float inv_a = 0.5f / fmaxf((float)B_DIM - cnt, 1.0f);

    const float4 g4  = *(const float4*)(gpt + (size_t)l * D_DIM + d0);
    const float4 gl4 = *(const float4*)(gpt + (size_t)L_DIM * D_DIM + d0);

    ushort4 ph, ah;
    ph.x = f2h(pos[0] * inv_p + 0.5f * g4.x);
    ph.y = f2h(pos[1] * inv_p + 0.5f * g4.y);
    ph.z = f2h(pos[2] * inv_p + 0.5f * g4.z);
    ph.w = f2h(pos[3] * inv_p + 0.5f * g4.w);
    ah.x = f2h((tot[0] - pos[0]) * inv_a + 0.5f * gl4.x);
    ah.y = f2h((tot[1] - pos[1]) * inv_a + 0.5f * gl4.y);
    ah.z = f2h((tot[2] - pos[2]) * inv_a + 0.5f * gl4.z);
    ah.w = f2h((tot[3] - pos[3]) * inv_a + 0.5f * gl4.w);

    *(ushort4*)(Vh + (size_t)l * D_DIM + d0) = ph;
    *(ushort4*)(Vh + (size_t)(L_DIM + l) * D_DIM + d0) = ah;

    if (t == 0) pos_cnt[l] = cnt;
}

// ---------------------------------------------------------------------------
// f16 MFMA GEMM: C[2048,768] = A[M,K](f16) @ B[N,K]^T(f16) + bias.
// Block tile 128x128, 4 waves each 64x64 (4x4 frags of 16x16x32), BK=32.
// gl_lds staging (linear LDS dest, XOR-swizzled global k-chunk src; same XOR
// on fragment reads), LDS double buffer.
// MODE 0: ReLU -> f16 H. MODE 1: proto rows -> masked d_out; anti rows ->
// weighted colsums into Partial; last anti block (atomic counter) finalizes.
// ---------------------------------------------------------------------------
template<int MODE>
__global__ __launch_bounds__(256)
void gemm_f16(const ushort* __restrict__ A, const ushort* __restrict__ B,
              const float* __restrict__ bias,
              ushort* __restrict__ OutH, float* __restrict__ OutF,
              float* __restrict__ Partial,
              const float* __restrict__ cnt, unsigned* __restrict__ counter)
{
    __shared__ ushort lds[2][8192];   // [buf][ A:128x32 | B:128x32 ]
    __shared__ float  colsum[4][64];
    __shared__ float  red[256];
    __shared__ unsigned lastflag;

    const int tid  = threadIdx.x;
    const int lane = tid & 63;
    const int wid  = tid >> 6;
    const int brow = blockIdx.y * 128;
    const int bcol = blockIdx.x * 128;
    const int wr   = (wid >> 1) * 64;   // 0,64
    const int wc   = (wid & 1) * 64;    // 0,64

    const int srow = tid >> 2;
    const int slot = tid & 3;
    const int sk   = (slot ^ ((srow >> 1) & 3)) * 8;   // swizzled k-chunk

    const ushort* pA0 = A + (size_t)(brow + srow) * K_DIM + sk;
    const ushort* pA1 = A + (size_t)(brow + 64 + srow) * K_DIM + sk;
    const ushort* pB0 = B + (size_t)(bcol + srow) * K_DIM + sk;
    const ushort* pB1 = B + (size_t)(bcol + 64 + srow) * K_DIM + sk;

    const int ldst = tid * 8;

    const int q   = lane >> 4;
    const int r15 = lane & 15;
    const int swz = ((q ^ ((r15 >> 1) & 3)) << 3);
    const int fA  = (wr + r15) * 32 + swz;            // + mi*512
    const int fB  = 4096 + (wc + r15) * 32 + swz;     // + ni*512

    floatx4 acc[4][4] = {};

    gl16(pA0, &lds[0][ldst]);
    gl16(pA1, &lds[0][2048 + ldst]);
    gl16(pB0, &lds[0][4096 + ldst]);
    gl16(pB1, &lds[0][6144 + ldst]);
    __syncthreads();

    for (int t = 0; t < NTILES; ++t) {
        const int cur = t & 1;
        if (t + 1 < NTILES) {
            const int ko = (t + 1) * 32;
            const int nxt = cur ^ 1;
            gl16(pA0 + ko, &lds[nxt][ldst]);
            gl16(pA1 + ko, &lds[nxt][2048 + ldst]);
            gl16(pB0 + ko, &lds[nxt][4096 + ldst]);
            gl16(pB1 + ko, &lds[nxt][6144 + ldst]);
        }
        half8 a[4], b[4];
        #pragma unroll
        for (int i = 0; i < 4; ++i) {
            a[i] = *(half8*)&lds[cur][fA + i * 512];
            b[i] = *(half8*)&lds[cur][fB + i * 512];
        }
        #pragma unroll
        for (int mi = 0; mi < 4; ++mi)
            #pragma unroll
            for (int ni = 0; ni < 4; ++ni)
                acc[mi][ni] = __builtin_amdgcn_mfma_f32_16x16x32_f16(a[mi], b[ni], acc[mi][ni], 0, 0, 0);
        __syncthreads();
    }

    if (MODE == 0 || brow < L_DIM) {
        #pragma unroll
        for (int mi = 0; mi < 4; ++mi) {
            #pragma unroll
            for (int ni = 0; ni < 4; ++ni) {
                const int col   = bcol + wc + ni * 16 + r15;
                const int rbase = brow + wr + mi * 16 + (q << 2);
                const float bv = bias[col];
                #pragma unroll
                for (int r = 0; r < 4; ++r) {
                    const float v = acc[mi][ni][r] + bv;
                    const int row = rbase + r;
                    if (MODE == 0) {
                        OutH[(size_t)row * D_DIM + col] = f2h(fmaxf(v, 0.f));
                    } else {
                        OutF[(size_t)row * D_DIM + col] = (cnt[row] > 0.f) ? v : 0.f;
                    }
                }
            }
        }
    } else {
        // anti half: weighted column sums over this block's 128 rows
        float s[4] = {0.f, 0.f, 0.f, 0.f};
        #pragma unroll
        for (int mi = 0; mi < 4; ++mi) {
            const int rbase = brow + wr + mi * 16 + (q << 2);
            #pragma unroll
            for (int r = 0; r < 4; ++r) {
                const float w = (cnt[rbase + r - L_DIM] < 255.5f) ? 1.0f : 0.0f;
                #pragma unroll
                for (int ni = 0; ni < 4; ++ni) {
                    const int col = bcol + wc + ni * 16 + r15;
                    s[ni] = fmaf(w, acc[mi][ni][r] + bias[col], s[ni]);
                }
            }
        }
        #pragma unroll
        for (int ni = 0; ni < 4; ++ni) {
            s[ni] += __shfl_down(s[ni], 32);
            s[ni] += __shfl_down(s[ni], 16);
            if (lane < 16) colsum[wid][ni * 16 + lane] = s[ni];
        }
        __syncthreads();
        if (tid < 128) {
            const float v = (tid < 64)
                ? colsum[0][tid] + colsum[2][tid]
                : colsum[1][tid - 64] + colsum[3][tid - 64];
            Partial[(size_t)(blockIdx.y - 8) * D_DIM + bcol + tid] = v;
        }
        __threadfence();
        __syncthreads();
        if (tid == 0) lastflag = (atomicAdd(counter, 1u) == 47u) ? 1u : 0u;
        __syncthreads();
        if (lastflag) {
            __threadfence();
            float w = 0.f;
            for (int i = tid; i < L_DIM; i += 256)
                w += (cnt[i] < 255.5f) ? 1.0f : 0.0f;
            red[tid] = w;
            __syncthreads();
            for (int st = 128; st > 0; st >>= 1) {
                if (tid < st) red[tid] += red[tid + st];
                __syncthreads();
            }
            const float wsum = fmaxf(red[0], 1.0f);
            #pragma unroll
            for (int j = 0; j < 3; ++j) {
                const int d = tid + j * 256;
                float sm = 0.f;
                #pragma unroll
                for (int pp = 0; pp < 8; ++pp)
                    sm += Partial[(size_t)pp * D_DIM + d];
                OutF[(size_t)L_DIM * D_DIM + d] = sm / wsum;
            }
        }
    }
}

// ---------------------------------------------------------------------------
extern "C" void kernel_launch(void* const* d_in, const int* in_sizes, int n_in,
                              void* d_out, int out_size, void* d_ws, size_t ws_size,
                              hipStream_t stream) {
    const float* x    = (const float*)d_in[0];
    const int*   mask = (const int*)d_in[1];
    const float* gpt  = (const float*)d_in[2];
    const float* W_h  = (const float*)d_in[3];
    const float* b_h  = (const float*)d_in[4];
    const float* W_p  = (const float*)d_in[5];
    const float* b_p  = (const float*)d_in[6];
    float* out = (float*)d_out;

    char* p = (char*)d_ws;
    ushort* Vh   = (ushort*)p; p += (size_t)2 * L_DIM * D_DIM * 2;
    ushort* Hh   = (ushort*)p; p += (size_t)2 * L_DIM * D_DIM * 2;
    ushort* WhH  = (ushort*)p; p += (size_t)WN * 2;
    ushort* WpH  = (ushort*)p; p += (size_t)WN * 2;
    float*  Part = (float*)p;  p += (size_t)8 * D_DIM * 4;
    float*  cnt  = (float*)p;  p += (size_t)L_DIM * 4;
    unsigned* counter = (unsigned*)p;

    reduce_and_cast<<<640, 768, 0, stream>>>(x, mask, gpt, W_h, W_p,
                                             Vh, WhH, WpH, cnt, counter);

    dim3 ggrid(D_DIM / 128, 2 * L_DIM / 128);
    gemm_f16<0><<<ggrid, 256, 0, stream>>>(Vh, WhH, b_h,
                                           Hh, nullptr, nullptr, nullptr, nullptr);
    gemm_f16<1><<<ggrid, 256, 0, stream>>>(Hh, WpH, b_p,
                                           nullptr, out, Part, cnt, counter);
}